// Round 5
// baseline (827.243 us; speedup 1.0000x reference)
//
#include <hip/hip_runtime.h>
#include <math.h>

#define LSEQ 1280
#define L0SEQ 1250
#define DM 64
#define NHEADS 4
#define DHD 16
#define NHASH 4
#define NBUK 20
#define NCHUNK 80
#define FFD 256
#define NBATCH 16
#define NBH 64

#define XSZ (NBATCH*LSEQ*DM)        // 1310720
#define QKSZ (NBH*LSEQ*DHD)         // 1310720
#define OHSZ (NBH*NHASH*LSEQ*DHD)   // 5242880
#define SLSZ (NBH*NHASH*LSEQ)       // 327680

typedef __attribute__((ext_vector_type(8))) short frag_ab;   // 8 bf16
typedef __attribute__((ext_vector_type(4))) float frag_c;    // 4 fp32

union FU { unsigned u[4]; frag_ab f; };

// exact triple split: x = h + m + l (bf16 each, truncation captures all 24 mantissa bits)
__device__ __forceinline__ void split3(float x, unsigned& h, unsigned& m, unsigned& l){
    unsigned bx = __float_as_uint(x);
    h = bx >> 16;
    float r = x - __uint_as_float(bx & 0xffff0000u);
    unsigned br = __float_as_uint(r);
    m = br >> 16;
    float r2 = r - __uint_as_float(br & 0xffff0000u);
    l = __float_as_uint(r2) >> 16;
}

__device__ __forceinline__ frag_ab pack8(const unsigned* s){  // 8 u16 values (low bits)
    FU R;
    #pragma unroll
    for (int i=0;i<4;i++) R.u[i] = s[2*i] | (s[2*i+1] << 16);
    return R.f;
}

// 8 u32 words each holding (h low16 | m high16) -> two frags
__device__ __forceinline__ void unpack_hm(const unsigned* p, frag_ab& fh, frag_ab& fm){
    FU H, M;
    #pragma unroll
    for (int i=0;i<4;i++){
        unsigned a = p[2*i], b = p[2*i+1];
        H.u[i] = (a & 0xffffu) | (b << 16);
        M.u[i] = (a >> 16) | (b & 0xffff0000u);
    }
    fh = H.f; fm = M.f;
}

__device__ __forceinline__ frag_ab fsel(bool c, frag_ab a, frag_ab b){
    FU A, B, R; A.f = a; B.f = b;
    #pragma unroll
    for (int i=0;i<4;i++) R.u[i] = c ? A.u[i] : B.u[i];
    return R.f;
}

// ---------------- embed: x = pad(wave^T) @ in_w + in_b ----------------
__global__ __launch_bounds__(256) void k_embed(
    const float* __restrict__ wave, const float* __restrict__ in_w,
    const float* __restrict__ in_b, float* __restrict__ x1, float* __restrict__ x2)
{
    int idx = blockIdx.x * 256 + threadIdx.x;   // over B*L*D
    int d = idx & 63;
    int t = idx >> 6;
    int b = t / LSEQ;
    int tt = t % LSEQ;
    float v0 = 0.f, v1 = 0.f;
    if (tt < L0SEQ) {
        v0 = wave[(size_t)(b*2+0)*L0SEQ + tt];
        v1 = wave[(size_t)(b*2+1)*L0SEQ + tt];
    }
    float x = v0 * in_w[d] + v1 * in_w[64 + d] + in_b[d];
    x1[idx] = x;
    x2[idx] = x;
}

// ---------------- LN + QK/V projection + LSH bucketing ----------------
// block = 64 tokens of one batch; grid 320
__global__ __launch_bounds__(256) void k_qkv(
    const float* __restrict__ x2, const float* __restrict__ g, const float* __restrict__ bta,
    const float* __restrict__ wqk, const float* __restrict__ wv, const float* __restrict__ rot,
    float* __restrict__ qk, float* __restrict__ v, int* __restrict__ buckets)
{
    __shared__ float xln[64][65];
    __shared__ float qkt[64][65];
    __shared__ float rots[640];
    __shared__ float psum[64][4];
    __shared__ float psq[64][4];
    int tid = threadIdx.x;
    int b  = blockIdx.x / 20;
    int t0 = (blockIdx.x % 20) * 64;
    const float* xbase = x2 + (size_t)(b*LSEQ + t0)*DM;
    int r = tid >> 2, qq = tid & 3;
    float vals[16];
    float s = 0.f, ss = 0.f;
    for (int i = 0; i < 16; i++) {
        float vv = xbase[r*DM + qq*16 + i];
        vals[i] = vv; s += vv; ss += vv*vv;
    }
    psum[r][qq] = s; psq[r][qq] = ss;
    for (int i = tid; i < 640; i += 256) rots[i] = rot[i];
    __syncthreads();
    float m  = (psum[r][0]+psum[r][1]+psum[r][2]+psum[r][3]) * (1.f/64.f);
    float vr = (psq[r][0]+psq[r][1]+psq[r][2]+psq[r][3]) * (1.f/64.f) - m*m;
    float rstd = 1.f / sqrtf(vr + 1e-5f);
    for (int i = 0; i < 16; i++) {
        int c = qq*16 + i;
        xln[r][c] = (vals[i]-m)*rstd*g[c] + bta[c];
    }
    __syncthreads();
    // matmuls: thread tile = 4 tokens x 4 cols
    int cg = tid & 15, tg = tid >> 4;
    int c0 = cg*4, tl0 = tg*4;
    float aq[4][4], av[4][4];
    for (int i=0;i<4;i++) for (int j=0;j<4;j++){ aq[i][j]=0.f; av[i][j]=0.f; }
    for (int f = 0; f < 64; f++) {
        float4 wq4 = *(const float4*)&wqk[f*64 + c0];
        float4 wv4 = *(const float4*)&wv [f*64 + c0];
        float xv[4];
        for (int i=0;i<4;i++) xv[i] = xln[tl0+i][f];
        for (int i=0;i<4;i++) {
            aq[i][0] += xv[i]*wq4.x; aq[i][1] += xv[i]*wq4.y;
            aq[i][2] += xv[i]*wq4.z; aq[i][3] += xv[i]*wq4.w;
            av[i][0] += xv[i]*wv4.x; av[i][1] += xv[i]*wv4.y;
            av[i][2] += xv[i]*wv4.z; av[i][3] += xv[i]*wv4.w;
        }
    }
    int head = c0 >> 4;
    int dh0  = c0 & 15;
    for (int i=0;i<4;i++) {
        int t = t0 + tl0 + i;
        float4 q4; q4.x=aq[i][0]; q4.y=aq[i][1]; q4.z=aq[i][2]; q4.w=aq[i][3];
        float4 v4; v4.x=av[i][0]; v4.y=av[i][1]; v4.z=av[i][2]; v4.w=av[i][3];
        *(float4*)&qk[((size_t)(b*NHEADS+head)*LSEQ + t)*DHD + dh0] = q4;
        *(float4*)&v [((size_t)(b*NHEADS+head)*LSEQ + t)*DHD + dh0] = v4;
        qkt[tl0+i][c0+0] = aq[i][0]; qkt[tl0+i][c0+1] = aq[i][1];
        qkt[tl0+i][c0+2] = aq[i][2]; qkt[tl0+i][c0+3] = aq[i][3];
    }
    __syncthreads();
    // buckets: thread = (token, head)
    int ttk = tid >> 2, hh = tid & 3;
    float qf[16];
    for (int f=0; f<16; f++) qf[f] = qkt[ttk][hh*16+f];
    int tglob = t0 + ttk;
    for (int nh = 0; nh < NHASH; nh++) {
        float rv[10];
        for (int i=0;i<10;i++) {
            float acc = 0.f;
            for (int f=0; f<16; f++) acc += qf[f]*rots[(f*NHASH+nh)*10 + i];
            rv[i] = acc;
        }
        float best = rv[0]; int bi = 0;
        for (int i=1;i<10;i++) if (rv[i] > best) { best = rv[i]; bi = i; }
        for (int i=0;i<10;i++) if (-rv[i] > best) { best = -rv[i]; bi = 10+i; }
        buckets[((size_t)(b*NHEADS+hh)*NHASH + nh)*LSEQ + tglob] = bi;
    }
}

// ---------------- counting sort per (bh, hash): stable, ballot-ranked ----------------
// one wave per (bh,hash) group; grid 256, block 64
__global__ __launch_bounds__(64) void k_sort(
    const int* __restrict__ buckets, int* __restrict__ sorted)
{
    __shared__ int hist[20];
    __shared__ int startl[20];
    int lane = threadIdx.x;
    int gidx = blockIdx.x;
    const int* bk = buckets + (size_t)gidx * LSEQ;
    int* dst = sorted + (size_t)gidx * LSEQ;
    if (lane < 20) hist[lane] = 0;
    __syncthreads();
    int myb[20];
    for (int ch = 0; ch < 20; ch++) {
        myb[ch] = bk[ch*64 + lane];
        atomicAdd(&hist[myb[ch]], 1);
    }
    __syncthreads();
    if (lane == 0) {
        int acc = 0;
        for (int b2 = 0; b2 < 20; b2++) { startl[b2] = acc; acc += hist[b2]; }
    }
    __syncthreads();
    unsigned long long below = (lane == 63) ? 0x7fffffffffffffffull
                                            : ((1ull << lane) - 1ull);
    for (int ch = 0; ch < 20; ch++) {
        int bv = myb[ch];
        unsigned long long mymask = 0, ownmask = 0;
        #pragma unroll
        for (int b2 = 0; b2 < 20; b2++) {
            unsigned long long m2 = __ballot(bv == b2);
            if (b2 == bv)   mymask  = m2;
            if (b2 == lane) ownmask = m2;
        }
        int rank = __popcll(mymask & below);
        int base = startl[bv];
        dst[base + rank] = ch*64 + lane;
        __syncthreads();
        if (lane < 20) startl[lane] += __popcll(ownmask);
        __syncthreads();
    }
}

// ---------------- chunked attention v5: MFMA, exact triple-split (h+m+l) ----------------
// one (bh, chunk) per block; grid 5120, block 256 (4 waves)
// k-slot packing: MFMA K=32 carries two split levels (slots 0-15 / 16-31);
// 3 MFMAs per tile give all cross-terms >= 2^-16; dropped terms <= 2^-24.
__global__ __launch_bounds__(256) void k_attn(
    const float* __restrict__ qk, const float* __restrict__ v,
    const int* __restrict__ sorted, float* __restrict__ o_hash, float* __restrict__ slog)
{
    __shared__ __align__(16) unsigned Kp[128*20];        // k-hat h|m, [key][dh], stride 20
    __shared__ __align__(16) unsigned Klo[128*10];       // k-hat lo pairs, [key][dh/2], stride 10
    __shared__ __align__(16) unsigned VTp[16*132];       // v^T h|m, [dh][key], stride 132
    __shared__ __align__(16) unsigned short VTlo[16*132];// v^T lo, [dh][key]
    __shared__ __align__(16) unsigned Pp[64*76];         // P h|m, [row][key-half], stride 76
    __shared__ __align__(16) unsigned short Plo[64*76];  // P lo
    __shared__ int kposS[128];

    int tid = threadIdx.x;
    int bh = blockIdx.x / NCHUNK;
    int c  = blockIdx.x % NCHUNK;
    int h  = c / NBUK, cc = c % NBUK;
    int cp = (c + NCHUNK - 1) % NCHUNK;
    int hp = cp / NBUK, ccp = cp % NBUK;
    if (tid < 64) {
        kposS[tid] = sorted[((size_t)bh*NHASH + h)*LSEQ + cc*64 + tid];
    } else if (tid < 128) {
        kposS[tid] = sorted[((size_t)bh*NHASH + hp)*LSEQ + ccp*64 + (tid-64)];
    }
    if (tid < 128) {
        int pos = kposS[tid];   // own write, no sync needed
        const float4* qrow = (const float4*)(qk + ((size_t)bh*LSEQ + pos)*DHD);
        float4 r0=qrow[0], r1=qrow[1], r2=qrow[2], r3=qrow[3];
        float rr[16] = {r0.x,r0.y,r0.z,r0.w, r1.x,r1.y,r1.z,r1.w,
                        r2.x,r2.y,r2.z,r2.w, r3.x,r3.y,r3.z,r3.w};
        float nsq = 0.f;
        #pragma unroll
        for (int e=0;e<16;e++) nsq += rr[e]*rr[e];
        float inv = 1.f / fmaxf(sqrtf(nsq), 1e-12f);
        unsigned sh[16], sm[16], sl[16];
        #pragma unroll
        for (int e=0;e<16;e++) split3(rr[e]*inv, sh[e], sm[e], sl[e]);
        #pragma unroll
        for (int e4=0;e4<4;e4++){
            uint4 t;
            t.x = sh[e4*4+0] | (sm[e4*4+0]<<16);
            t.y = sh[e4*4+1] | (sm[e4*4+1]<<16);
            t.z = sh[e4*4+2] | (sm[e4*4+2]<<16);
            t.w = sh[e4*4+3] | (sm[e4*4+3]<<16);
            *(uint4*)&Kp[tid*20 + e4*4] = t;
        }
        #pragma unroll
        for (int e2=0;e2<4;e2++){
            uint2 t;
            t.x = sl[e2*4+0] | (sl[e2*4+1]<<16);
            t.y = sl[e2*4+2] | (sl[e2*4+3]<<16);
            *(uint2*)&Klo[tid*10 + e2*2] = t;
        }
        const float4* vrow = (const float4*)(v + ((size_t)bh*LSEQ + pos)*DHD);
        float4 v0=vrow[0], v1=vrow[1], v2=vrow[2], v3=vrow[3];
        float vvv[16] = {v0.x,v0.y,v0.z,v0.w, v1.x,v1.y,v1.z,v1.w,
                         v2.x,v2.y,v2.z,v2.w, v3.x,v3.y,v3.z,v3.w};
        #pragma unroll
        for (int d=0;d<16;d++){
            unsigned vh_, vm_, vl_;
            split3(vvv[d], vh_, vm_, vl_);
            VTp[d*132 + tid] = vh_ | (vm_<<16);
            VTlo[d*132 + tid] = (unsigned short)vl_;
        }
    }
    __syncthreads();

    int w = tid >> 6, lane = tid & 63;
    int quad = lane >> 4, col = lane & 15;
    bool lowq = (quad < 2);

    // Q frags from global (gather; L1-served). 0.25 folded into q (exact, pow2).
    int qrow_pos = kposS[16*w + col];
    const float4* qr = (const float4*)(qk + ((size_t)bh*LSEQ + qrow_pos)*DHD + (quad&1)*8);
    float4 qv0 = qr[0], qv1 = qr[1];
    float qx[8] = {qv0.x,qv0.y,qv0.z,qv0.w, qv1.x,qv1.y,qv1.z,qv1.w};
    unsigned qh16[8], qm16[8], ql16[8];
    #pragma unroll
    for (int i=0;i<8;i++) split3(qx[i]*0.25f, qh16[i], qm16[i], ql16[i]);
    frag_ab QH = pack8(qh16), QM = pack8(qm16), QL = pack8(ql16);
    frag_ab qA1 = fsel(lowq, QH, QM);   // [qh|qm]
    frag_ab qA2 = fsel(lowq, QH, QL);   // [qh|ql]
    frag_ab qA3 = fsel(lowq, QM, QH);   // [qm|qh]

    frag_c acc[8];
    #pragma unroll
    for (int nt=0; nt<8; nt++){
        int krow = nt*16 + col;
        const unsigned* kp = &Kp[krow*20 + (quad&1)*8];
        uint4 a0 = *(const uint4*)kp, a1 = *(const uint4*)(kp+4);
        unsigned p8[8] = {a0.x,a0.y,a0.z,a0.w, a1.x,a1.y,a1.z,a1.w};
        frag_ab KH, KM; unpack_hm(p8, KH, KM);
        const uint2* klp = (const uint2*)&Klo[krow*10 + (quad&1)*4];
        uint2 l0 = klp[0], l1 = klp[1];
        FU LF; LF.u[0]=l0.x; LF.u[1]=l0.y; LF.u[2]=l1.x; LF.u[3]=l1.y;
        frag_ab KL = LF.f;
        frag_ab kB1 = fsel(lowq, KH, KM);   // [kh|km]
        frag_ab kB2 = fsel(lowq, KM, KH);   // [km|kh]
        frag_ab kB3 = fsel(lowq, KH, KL);   // [kh|kl]
        frag_c a = {0.f,0.f,0.f,0.f};
        a = __builtin_amdgcn_mfma_f32_16x16x32_bf16(qA1, kB1, a, 0, 0, 0);
        a = __builtin_amdgcn_mfma_f32_16x16x32_bf16(qA2, kB2, a, 0, 0, 0);
        a = __builtin_amdgcn_mfma_f32_16x16x32_bf16(qA3, kB3, a, 0, 0, 0);
        acc[nt] = a;
    }
    // self-mask: lane holds rows 16w + quad*4 + reg, key col = nt*16 + col
    int qp[4];
    #pragma unroll
    for (int reg=0; reg<4; reg++) qp[reg] = kposS[16*w + quad*4 + reg];
    #pragma unroll
    for (int nt=0; nt<8; nt++){
        int kp2 = kposS[nt*16 + col];
        #pragma unroll
        for (int reg=0; reg<4; reg++)
            if (kp2 == qp[reg]) acc[nt][reg] = -5e4f;
    }
    // softmax over 128 = 8 tiles (in-lane) x 16 lanes (cols)
    float mx[4] = {-3.4e38f,-3.4e38f,-3.4e38f,-3.4e38f};
    #pragma unroll
    for (int nt=0; nt<8; nt++)
        #pragma unroll
        for (int reg=0; reg<4; reg++) mx[reg] = fmaxf(mx[reg], acc[nt][reg]);
    #pragma unroll
    for (int reg=0; reg<4; reg++){
        float m2 = mx[reg];
        m2 = fmaxf(m2, __shfl_xor(m2, 1)); m2 = fmaxf(m2, __shfl_xor(m2, 2));
        m2 = fmaxf(m2, __shfl_xor(m2, 4)); m2 = fmaxf(m2, __shfl_xor(m2, 8));
        mx[reg] = m2;
    }
    float sm2[4] = {0.f,0.f,0.f,0.f};
    #pragma unroll
    for (int nt=0; nt<8; nt++)
        #pragma unroll
        for (int reg=0; reg<4; reg++){
            float e = __expf(acc[nt][reg] - mx[reg]);
            acc[nt][reg] = e; sm2[reg] += e;
        }
    #pragma unroll
    for (int reg=0; reg<4; reg++){
        float s2 = sm2[reg];
        s2 += __shfl_xor(s2, 1); s2 += __shfl_xor(s2, 2);
        s2 += __shfl_xor(s2, 4); s2 += __shfl_xor(s2, 8);
        sm2[reg] = s2;
    }
    float invs[4];
    #pragma unroll
    for (int reg=0; reg<4; reg++) invs[reg] = 1.f / sm2[reg];
    if (col == 0) {
        #pragma unroll
        for (int reg=0; reg<4; reg++)
            slog[((size_t)bh*NHASH + h)*LSEQ + qp[reg]] = mx[reg] + __logf(sm2[reg]);
    }
    // PV in two 64-key halves through the P half-buffer
    frag_c o = {0.f,0.f,0.f,0.f};
    #pragma unroll
    for (int H=0; H<2; H++){
        #pragma unroll
        for (int nt2=0; nt2<4; nt2++){
            int ntg = H*4 + nt2;
            #pragma unroll
            for (int reg=0; reg<4; reg++){
                float p = acc[ntg][reg] * invs[reg];
                unsigned ph_, pm_, pl_;
                split3(p, ph_, pm_, pl_);
                int r2 = 16*w + quad*4 + reg;
                int kc = nt2*16 + col;
                Pp[r2*76 + kc] = ph_ | (pm_<<16);
                Plo[r2*76 + kc] = (unsigned short)pl_;
            }
        }
        __syncthreads();
        #pragma unroll
        for (int kt=0; kt<4; kt++){
            const unsigned* pp = &Pp[(16*w + col)*76 + kt*16 + (quad&1)*8];
            uint4 x0 = *(const uint4*)pp, x1 = *(const uint4*)(pp+4);
            unsigned p8[8] = {x0.x,x0.y,x0.z,x0.w, x1.x,x1.y,x1.z,x1.w};
            frag_ab PH, PM; unpack_hm(p8, PH, PM);
            const uint2* plp = (const uint2*)&Plo[(16*w + col)*76 + kt*16 + (quad&1)*8];
            uint2 z0 = plp[0], z1 = plp[1];
            FU PLF; PLF.u[0]=z0.x; PLF.u[1]=z0.y; PLF.u[2]=z1.x; PLF.u[3]=z1.y;
            frag_ab PL = PLF.f;
            int kb = H*64 + kt*16 + (quad&1)*8;
            const unsigned* vp = &VTp[col*132 + kb];
            uint4 y0 = *(const uint4*)vp, y1 = *(const uint4*)(vp+4);
            unsigned v8[8] = {y0.x,y0.y,y0.z,y0.w, y1.x,y1.y,y1.z,y1.w};
            frag_ab VH, VM; unpack_hm(v8, VH, VM);
            const uint2* vlp = (const uint2*)&VTlo[col*132 + kb];
            uint2 u0 = vlp[0], u1 = vlp[1];
            FU VLF; VLF.u[0]=u0.x; VLF.u[1]=u0.y; VLF.u[2]=u1.x; VLF.u[3]=u1.y;
            frag_ab VL = VLF.f;
            frag_ab A1 = fsel(lowq, PH, PM);    // [ph|pm]
            frag_ab A2 = fsel(lowq, PH, PL);    // [ph|pl]
            frag_ab A3 = fsel(lowq, PM, PH);    // [pm|ph]
            frag_ab B1 = fsel(lowq, VH, VM);    // [vh|vm]
            frag_ab B2 = fsel(lowq, VM, VH);    // [vm|vh]
            frag_ab B3 = fsel(lowq, VH, VL);    // [vh|vl]
            o = __builtin_amdgcn_mfma_f32_16x16x32_bf16(A1, B1, o, 0, 0, 0);
            o = __builtin_amdgcn_mfma_f32_16x16x32_bf16(A2, B2, o, 0, 0, 0);
            o = __builtin_amdgcn_mfma_f32_16x16x32_bf16(A3, B3, o, 0, 0, 0);
        }
        __syncthreads();
    }
    size_t obase = ((size_t)bh*NHASH + h)*LSEQ;
    #pragma unroll
    for (int reg=0; reg<4; reg++)
        o_hash[(obase + qp[reg])*DHD + col] = o[reg];
}

// ---------------- hash-round combine + output proj + residual into x1 ----------------
// block = 64 tokens of one batch; grid 320
__global__ __launch_bounds__(256) void k_combine(
    const float* __restrict__ o_hash, const float* __restrict__ slog,
    const float* __restrict__ wo_w, const float* __restrict__ wo_b, float* __restrict__ x1)
{
    __shared__ float att[64][65];
    int tid = threadIdx.x;
    int b  = blockIdx.x / 20;
    int t0 = (blockIdx.x % 20) * 64;
    int ttk = tid >> 2, head = tid & 3;
    int t = t0 + ttk;
    int bh = b*NHEADS + head;
    float sl[4];
    for (int nh=0;nh<4;nh++) sl[nh] = slog[((size_t)bh*NHASH + nh)*LSEQ + t];
    float mx = fmaxf(fmaxf(sl[0],sl[1]), fmaxf(sl[2],sl[3]));
    float wsum = 0.f; float wv[4];
    for (int nh=0;nh<4;nh++){ wv[nh] = __expf(sl[nh]-mx); wsum += wv[nh]; }
    float invs = 1.f/wsum;
    float a[16];
    for (int d=0;d<16;d++) a[d]=0.f;
    for (int nh=0;nh<4;nh++){
        const float4* orow = (const float4*)(o_hash + (((size_t)bh*NHASH + nh)*LSEQ + t)*DHD);
        float wn = wv[nh]*invs;
        float4 A=orow[0], B=orow[1], C=orow[2], Dq=orow[3];
        a[0]+=wn*A.x;  a[1]+=wn*A.y;  a[2]+=wn*A.z;  a[3]+=wn*A.w;
        a[4]+=wn*B.x;  a[5]+=wn*B.y;  a[6]+=wn*B.z;  a[7]+=wn*B.w;
        a[8]+=wn*C.x;  a[9]+=wn*C.y;  a[10]+=wn*C.z; a[11]+=wn*C.w;
        a[12]+=wn*Dq.x;a[13]+=wn*Dq.y;a[14]+=wn*Dq.z;a[15]+=wn*Dq.w;
    }
    for (int d=0;d<16;d++) att[ttk][head*16+d] = a[d];
    __syncthreads();
    int cg = tid & 15, tg = tid >> 4;
    int c0 = cg*4, tl0 = tg*4;
    float acc[4][4];
    for (int i=0;i<4;i++) for (int j=0;j<4;j++) acc[i][j]=0.f;
    for (int f=0; f<64; f++){
        float4 w4 = *(const float4*)&wo_w[f*64 + c0];
        float xv[4];
        for (int i=0;i<4;i++) xv[i] = att[tl0+i][f];
        for (int i=0;i<4;i++){
            acc[i][0]+=xv[i]*w4.x; acc[i][1]+=xv[i]*w4.y;
            acc[i][2]+=xv[i]*w4.z; acc[i][3]+=xv[i]*w4.w;
        }
    }
    float4 bb = *(const float4*)&wo_b[c0];
    for (int i=0;i<4;i++){
        size_t idx = ((size_t)b*LSEQ + (t0 + tl0 + i))*DM + c0;
        float4 cur = *(float4*)&x1[idx];
        cur.x += acc[i][0]+bb.x; cur.y += acc[i][1]+bb.y;
        cur.z += acc[i][2]+bb.z; cur.w += acc[i][3]+bb.w;
        *(float4*)&x1[idx] = cur;
    }
}

// ---------------- LN2 + W1 + gelu -> mid ----------------
// block = 32 tokens; grid 640
__global__ __launch_bounds__(256) void k_ff1(
    const float* __restrict__ x1, const float* __restrict__ g, const float* __restrict__ bta,
    const float* __restrict__ w1, const float* __restrict__ b1, float* __restrict__ mid)
{
    __shared__ float w1s[16*256];
    __shared__ float xln[32][65];
    __shared__ float ps[32][8], pq[32][8];
    int tid = threadIdx.x;
    int tbase = blockIdx.x * 32;
    int r = tid >> 3, qq = tid & 7;
    const float* xr = x1 + (size_t)(tbase + r)*DM;
    float vals[8]; float s = 0.f, ss = 0.f;
    for (int i=0;i<8;i++){ float vv = xr[qq*8+i]; vals[i]=vv; s+=vv; ss+=vv*vv; }
    ps[r][qq]=s; pq[r][qq]=ss;
    __syncthreads();
    float m=0.f, vr=0.f;
    for (int k2=0;k2<8;k2++){ m+=ps[r][k2]; vr+=pq[r][k2]; }
    m *= (1.f/64.f); vr = vr*(1.f/64.f) - m*m;
    float rstd = 1.f/sqrtf(vr+1e-5f);
    for (int i=0;i<8;i++){ int cidx=qq*8+i; xln[r][cidx] = (vals[i]-m)*rstd*g[cidx]+bta[cidx]; }
    float acc[4][8];
    for (int i=0;i<4;i++) for (int k2=0;k2<8;k2++) acc[i][k2]=0.f;
    int tg = tid >> 5;      // 8 groups of 4 tokens
    int cg = tid & 31;      // out col = cg + 32*k2
    int tl0 = tg*4;
    for (int fc = 0; fc < 4; fc++) {
        __syncthreads();
        for (int j = tid; j < 1024; j += 256)
            *(float4*)&w1s[j*4] = *(const float4*)&w1[fc*4096 + j*4];
        __syncthreads();
        for (int fl = 0; fl < 16; fl++) {
            int f = fc*16 + fl;
            float xv[4];
            for (int i=0;i<4;i++) xv[i] = xln[tl0+i][f];
            for (int k2=0;k2<8;k2++) {
                float wvv = w1s[fl*256 + cg + 32*k2];
                for (int i=0;i<4;i++) acc[i][k2] += xv[i]*wvv;
            }
        }
    }
    for (int k2=0;k2<8;k2++){
        int cidx = cg + 32*k2;
        float bb = b1[cidx];
        for (int i=0;i<4;i++){
            float xx = acc[i][k2] + bb;
            float ge = 0.5f*xx*(1.f + erff(xx*0.70710678118654752f));
            mid[(size_t)(tbase + tl0 + i)*FFD + cidx] = ge;
        }
    }
}

// ---------------- mid @ W2 + b2 -> residual into x2 ----------------
// block = 64 tokens; grid 320
__global__ __launch_bounds__(256) void k_ff2(
    const float* __restrict__ mid, const float* __restrict__ w2, const float* __restrict__ b2,
    float* __restrict__ x2)
{
    __shared__ float mids[64][65];
    int tid = threadIdx.x;
    int tbase = blockIdx.x * 64;
    int tg = tid >> 4, cg = tid & 15;
    int tl0 = tg*4, c0 = cg*4;
    float acc[4][4];
    for (int i=0;i<4;i++) for (int j=0;j<4;j++) acc[i][j]=0.f;
    for (int fc = 0; fc < 4; fc++) {
        __syncthreads();
        for (int j = tid; j < 1024; j += 256) {
            int row = j >> 4; int col4 = (j & 15) * 4;
            float4 vv = *(const float4*)&mid[(size_t)(tbase+row)*FFD + fc*64 + col4];
            mids[row][col4+0]=vv.x; mids[row][col4+1]=vv.y;
            mids[row][col4+2]=vv.z; mids[row][col4+3]=vv.w;
        }
        __syncthreads();
        for (int fl = 0; fl < 64; fl++) {
            float4 wv4 = *(const float4*)&w2[(fc*64+fl)*64 + c0];
            float mv[4];
            for (int i=0;i<4;i++) mv[i] = mids[tl0+i][fl];
            for (int i=0;i<4;i++){
                acc[i][0]+=mv[i]*wv4.x; acc[i][1]+=mv[i]*wv4.y;
                acc[i][2]+=mv[i]*wv4.z; acc[i][3]+=mv[i]*wv4.w;
            }
        }
    }
    float4 bb = *(const float4*)&b2[c0];
    for (int i=0;i<4;i++){
        size_t idx = ((size_t)(tbase + tl0 + i))*DM + c0;
        float4 cur = *(float4*)&x2[idx];
        cur.x += acc[i][0]+bb.x; cur.y += acc[i][1]+bb.y;
        cur.z += acc[i][2]+bb.z; cur.w += acc[i][3]+bb.w;
        *(float4*)&x2[idx] = cur;
    }
}

// ---------------- output proj: y = 0.5*(x1+x2) @ out_w + out_b, crop to 1250 ----------------
__global__ __launch_bounds__(256) void k_out(
    const float* __restrict__ x1, const float* __restrict__ x2,
    const float* __restrict__ out_w, const float* __restrict__ out_b, float* __restrict__ y)
{
    int idx = blockIdx.x * 256 + threadIdx.x;
    if (idx >= NBATCH * L0SEQ) return;
    int b = idx / L0SEQ, t = idx % L0SEQ;
    const float* r1 = x1 + ((size_t)b*LSEQ + t)*DM;
    const float* r2 = x2 + ((size_t)b*LSEQ + t)*DM;
    float s = 0.f;
    for (int d = 0; d < DM; d++) s += (r1[d]+r2[d])*0.5f*out_w[d];
    y[idx] = s + out_b[0];
}

extern "C" void kernel_launch(void* const* d_in, const int* in_sizes, int n_in,
                              void* d_out, int out_size, void* d_ws, size_t ws_size,
                              hipStream_t stream)
{
    const float* wave  = (const float*)d_in[0];
    const float* in_w  = (const float*)d_in[1];
    const float* in_b  = (const float*)d_in[2];
    const float* ln1_g = (const float*)d_in[3];
    const float* ln1_b = (const float*)d_in[4];
    const float* wqk   = (const float*)d_in[5];
    const float* wv    = (const float*)d_in[6];
    const float* wo_w  = (const float*)d_in[7];
    const float* wo_b  = (const float*)d_in[8];
    const float* rot   = (const float*)d_in[9];
    const float* ln2_g = (const float*)d_in[10];
    const float* ln2_b = (const float*)d_in[11];
    const float* w1    = (const float*)d_in[12];
    const float* b1    = (const float*)d_in[13];
    const float* w2    = (const float*)d_in[14];
    const float* b2    = (const float*)d_in[15];
    const float* out_w = (const float*)d_in[16];
    const float* out_b = (const float*)d_in[17];
    float* y = (float*)d_out;

    float* ws = (float*)d_ws;
    float* x1     = ws;                  // XSZ
    float* x2     = x1 + XSZ;            // XSZ
    float* qkb    = x2 + XSZ;            // QKSZ
    float* vb     = qkb + QKSZ;          // QKSZ
    float* o_hash = vb + QKSZ;           // OHSZ
    float* slogb  = o_hash + OHSZ;       // SLSZ
    int* buckets  = (int*)(slogb + SLSZ); // SLSZ ints
    int* sorted   = buckets + SLSZ;      // SLSZ ints
    float* mid    = o_hash;              // reuse (disjoint lifetime within a layer)

    k_embed<<<XSZ/256, 256, 0, stream>>>(wave, in_w, in_b, x1, x2);
    for (int layer = 0; layer < 4; layer++) {
        k_qkv<<<320, 256, 0, stream>>>(x2, ln1_g + layer*64, ln1_b + layer*64,
                                       wqk + layer*4096, wv + layer*4096, rot + layer*640,
                                       qkb, vb, buckets);
        k_sort<<<256, 64, 0, stream>>>(buckets, sorted);
        k_attn<<<NBH*NCHUNK, 256, 0, stream>>>(qkb, vb, sorted, o_hash, slogb);
        k_combine<<<320, 256, 0, stream>>>(o_hash, slogb, wo_w + layer*4096, wo_b + layer*64, x1);
        k_ff1<<<640, 256, 0, stream>>>(x1, ln2_g + layer*64, ln2_b + layer*64,
                                       w1 + layer*16384, b1 + layer*256, mid);
        k_ff2<<<320, 256, 0, stream>>>(mid, w2 + layer*16384, b2 + layer*64, x2);
    }
    k_out<<<(NBATCH*L0SEQ + 255)/256, 256, 0, stream>>>(x1, x2, out_w, out_b, y);
}

// Round 6
// 720.774 us; speedup vs baseline: 1.1477x; 1.1477x over previous
//
#include <hip/hip_runtime.h>
#include <math.h>

#define LSEQ 1280
#define L0SEQ 1250
#define DM 64
#define NHEADS 4
#define DHD 16
#define NHASH 4
#define NBUK 20
#define NCHUNK 80
#define FFD 256
#define NBATCH 16
#define NBH 64

#define XSZ (NBATCH*LSEQ*DM)        // 1310720
#define QKSZ (NBH*LSEQ*DHD)         // 1310720
#define OHSZ (NBH*NHASH*LSEQ*DHD)   // 5242880
#define SLSZ (NBH*NHASH*LSEQ)       // 327680

typedef __attribute__((ext_vector_type(8))) short frag_ab;   // 8 bf16
typedef __attribute__((ext_vector_type(4))) float frag_c;    // 4 fp32

union FU4 { uint4 v; frag_ab f; };

// round-to-nearest bf16 (returns low 16 bits)
__device__ __forceinline__ unsigned rnbf(float x){
    unsigned b = __float_as_uint(x);
    return (b + 0x7fffu + ((b >> 16) & 1u)) >> 16;
}
__device__ __forceinline__ float bf2f(unsigned h){ return __uint_as_float(h << 16); }

// exact triple split (truncation): x = h + m + l
__device__ __forceinline__ void split3(float x, unsigned& h, unsigned& m, unsigned& l){
    unsigned bx = __float_as_uint(x);
    h = bx >> 16;
    float r = x - __uint_as_float(bx & 0xffff0000u);
    unsigned br = __float_as_uint(r);
    m = br >> 16;
    float r2 = r - __uint_as_float(br & 0xffff0000u);
    l = __float_as_uint(r2) >> 16;
}

// ---------------- embed: x = pad(wave^T) @ in_w + in_b ----------------
__global__ __launch_bounds__(256) void k_embed(
    const float* __restrict__ wave, const float* __restrict__ in_w,
    const float* __restrict__ in_b, float* __restrict__ x1, float* __restrict__ x2)
{
    int idx = blockIdx.x * 256 + threadIdx.x;   // over B*L*D
    int d = idx & 63;
    int t = idx >> 6;
    int b = t / LSEQ;
    int tt = t % LSEQ;
    float v0 = 0.f, v1 = 0.f;
    if (tt < L0SEQ) {
        v0 = wave[(size_t)(b*2+0)*L0SEQ + tt];
        v1 = wave[(size_t)(b*2+1)*L0SEQ + tt];
    }
    float x = v0 * in_w[d] + v1 * in_w[64 + d] + in_b[d];
    x1[idx] = x;
    x2[idx] = x;
}

// ---------------- LN + QK/V projection + LSH bucketing ----------------
// block = 64 tokens of one batch; grid 320
__global__ __launch_bounds__(256) void k_qkv(
    const float* __restrict__ x2, const float* __restrict__ g, const float* __restrict__ bta,
    const float* __restrict__ wqk, const float* __restrict__ wv, const float* __restrict__ rot,
    float* __restrict__ qk, float* __restrict__ v, int* __restrict__ buckets)
{
    __shared__ float xln[64][65];
    __shared__ float qkt[64][65];
    __shared__ float rots[640];
    __shared__ float psum[64][4];
    __shared__ float psq[64][4];
    int tid = threadIdx.x;
    int b  = blockIdx.x / 20;
    int t0 = (blockIdx.x % 20) * 64;
    const float* xbase = x2 + (size_t)(b*LSEQ + t0)*DM;
    int r = tid >> 2, qq = tid & 3;
    float vals[16];
    float s = 0.f, ss = 0.f;
    for (int i = 0; i < 16; i++) {
        float vv = xbase[r*DM + qq*16 + i];
        vals[i] = vv; s += vv; ss += vv*vv;
    }
    psum[r][qq] = s; psq[r][qq] = ss;
    for (int i = tid; i < 640; i += 256) rots[i] = rot[i];
    __syncthreads();
    float m  = (psum[r][0]+psum[r][1]+psum[r][2]+psum[r][3]) * (1.f/64.f);
    float vr = (psq[r][0]+psq[r][1]+psq[r][2]+psq[r][3]) * (1.f/64.f) - m*m;
    float rstd = 1.f / sqrtf(vr + 1e-5f);
    for (int i = 0; i < 16; i++) {
        int c = qq*16 + i;
        xln[r][c] = (vals[i]-m)*rstd*g[c] + bta[c];
    }
    __syncthreads();
    // matmuls: thread tile = 4 tokens x 4 cols
    int cg = tid & 15, tg = tid >> 4;
    int c0 = cg*4, tl0 = tg*4;
    float aq[4][4], av[4][4];
    for (int i=0;i<4;i++) for (int j=0;j<4;j++){ aq[i][j]=0.f; av[i][j]=0.f; }
    for (int f = 0; f < 64; f++) {
        float4 wq4 = *(const float4*)&wqk[f*64 + c0];
        float4 wv4 = *(const float4*)&wv [f*64 + c0];
        float xv[4];
        for (int i=0;i<4;i++) xv[i] = xln[tl0+i][f];
        for (int i=0;i<4;i++) {
            aq[i][0] += xv[i]*wq4.x; aq[i][1] += xv[i]*wq4.y;
            aq[i][2] += xv[i]*wq4.z; aq[i][3] += xv[i]*wq4.w;
            av[i][0] += xv[i]*wv4.x; av[i][1] += xv[i]*wv4.y;
            av[i][2] += xv[i]*wv4.z; av[i][3] += xv[i]*wv4.w;
        }
    }
    int head = c0 >> 4;
    int dh0  = c0 & 15;
    for (int i=0;i<4;i++) {
        int t = t0 + tl0 + i;
        float4 q4; q4.x=aq[i][0]; q4.y=aq[i][1]; q4.z=aq[i][2]; q4.w=aq[i][3];
        float4 v4; v4.x=av[i][0]; v4.y=av[i][1]; v4.z=av[i][2]; v4.w=av[i][3];
        *(float4*)&qk[((size_t)(b*NHEADS+head)*LSEQ + t)*DHD + dh0] = q4;
        *(float4*)&v [((size_t)(b*NHEADS+head)*LSEQ + t)*DHD + dh0] = v4;
        qkt[tl0+i][c0+0] = aq[i][0]; qkt[tl0+i][c0+1] = aq[i][1];
        qkt[tl0+i][c0+2] = aq[i][2]; qkt[tl0+i][c0+3] = aq[i][3];
    }
    __syncthreads();
    // buckets: thread = (token, head)
    int ttk = tid >> 2, hh = tid & 3;
    float qf[16];
    for (int f=0; f<16; f++) qf[f] = qkt[ttk][hh*16+f];
    int tglob = t0 + ttk;
    for (int nh = 0; nh < NHASH; nh++) {
        float rv[10];
        for (int i=0;i<10;i++) {
            float acc = 0.f;
            for (int f=0; f<16; f++) acc += qf[f]*rots[(f*NHASH+nh)*10 + i];
            rv[i] = acc;
        }
        float best = rv[0]; int bi = 0;
        for (int i=1;i<10;i++) if (rv[i] > best) { best = rv[i]; bi = i; }
        for (int i=0;i<10;i++) if (-rv[i] > best) { best = -rv[i]; bi = 10+i; }
        buckets[((size_t)(b*NHEADS+hh)*NHASH + nh)*LSEQ + tglob] = bi;
    }
}

// ---------------- counting sort per (bh, hash): stable, ballot-ranked ----------------
// one wave per (bh,hash) group; grid 256, block 64
__global__ __launch_bounds__(64) void k_sort(
    const int* __restrict__ buckets, int* __restrict__ sorted)
{
    __shared__ int hist[20];
    __shared__ int startl[20];
    int lane = threadIdx.x;
    int gidx = blockIdx.x;
    const int* bk = buckets + (size_t)gidx * LSEQ;
    int* dst = sorted + (size_t)gidx * LSEQ;
    if (lane < 20) hist[lane] = 0;
    __syncthreads();
    int myb[20];
    for (int ch = 0; ch < 20; ch++) {
        myb[ch] = bk[ch*64 + lane];
        atomicAdd(&hist[myb[ch]], 1);
    }
    __syncthreads();
    if (lane == 0) {
        int acc = 0;
        for (int b2 = 0; b2 < 20; b2++) { startl[b2] = acc; acc += hist[b2]; }
    }
    __syncthreads();
    unsigned long long below = (lane == 63) ? 0x7fffffffffffffffull
                                            : ((1ull << lane) - 1ull);
    for (int ch = 0; ch < 20; ch++) {
        int bv = myb[ch];
        unsigned long long mymask = 0, ownmask = 0;
        #pragma unroll
        for (int b2 = 0; b2 < 20; b2++) {
            unsigned long long m2 = __ballot(bv == b2);
            if (b2 == bv)   mymask  = m2;
            if (b2 == lane) ownmask = m2;
        }
        int rank = __popcll(mymask & below);
        int base = startl[bv];
        dst[base + rank] = ch*64 + lane;
        __syncthreads();
        if (lane < 20) startl[lane] += __popcll(ownmask);
        __syncthreads();
    }
}

// ---------------- chunked attention v6: MFMA with pre-baked interleaved operands ----------------
// one (bh, chunk) per block; grid 5120, block 256 (4 waves)
// k-slot pairing: slot 2i = (elem i, level X), 2i+1 = (elem i, level Y) -> every frag is one b128.
// QK: RN-2 splits, 2 MFMA/tile (all 4 cross terms). PV: exact trunc-3 splits, 3 MFMA/tile
// (terms {hh,mm},{hm,mh},{hl,lh}; dropped <=2^-24 -- same numerics as v5, absmax 6.1e-5).
__global__ __launch_bounds__(256) void k_attn(
    const float* __restrict__ qk, const float* __restrict__ v,
    const int* __restrict__ sorted, float* __restrict__ o_hash, float* __restrict__ slog)
{
    // 13120 u32 = 52480 B total -> 3 blocks/CU
    __shared__ __align__(16) unsigned SMEM[13120];
    unsigned* Va1 = SMEM;              // [kt 8][dh 16][key 16 u32] kt-stride 328, dh-stride 20
    unsigned* Va2 = SMEM + 2624;
    unsigned* Va3 = SMEM + 5248;
    unsigned* Ka1 = SMEM + 7872;       // [key 128][dh 16 u32] stride 20  (phase 1)
    unsigned* Ka2 = SMEM + 10432;
    unsigned* Pa1 = SMEM + 7872;       // [ktL 2][row 64][key 16 u32] stride 20 (phase 2, alias)
    unsigned* Pa2 = SMEM + 10432;
    int* kposS = (int*)(SMEM + 12992); // 128 ints

    int tid = threadIdx.x;
    int bh = blockIdx.x / NCHUNK;
    int c  = blockIdx.x % NCHUNK;
    int h  = c / NBUK, cc = c % NBUK;
    int cp = (c + NCHUNK - 1) % NCHUNK;
    int hp = cp / NBUK, ccp = cp % NBUK;

    int key = tid & 127;
    int pos = (key < 64)
        ? sorted[((size_t)bh*NHASH + h)*LSEQ + cc*64 + key]
        : sorted[((size_t)bh*NHASH + hp)*LSEQ + ccp*64 + (key-64)];
    if (tid < 128) {
        kposS[key] = pos;
        // ---- K stager: k-hat RN-2 split, interleaved [kh|kl] / [kl|kh] ----
        const float4* qrow = (const float4*)(qk + ((size_t)bh*LSEQ + pos)*DHD);
        float4 r0=qrow[0], r1=qrow[1], r2=qrow[2], r3=qrow[3];
        float rr[16] = {r0.x,r0.y,r0.z,r0.w, r1.x,r1.y,r1.z,r1.w,
                        r2.x,r2.y,r2.z,r2.w, r3.x,r3.y,r3.z,r3.w};
        float nsq = 0.f;
        #pragma unroll
        for (int e=0;e<16;e++) nsq += rr[e]*rr[e];
        float inv = 1.f / fmaxf(sqrtf(nsq), 1e-12f);
        unsigned w1a[16], w2a[16];
        #pragma unroll
        for (int e=0;e<16;e++){
            float x = rr[e]*inv;
            unsigned kh = rnbf(x);
            unsigned kl = rnbf(x - bf2f(kh));
            w1a[e] = kh | (kl<<16);
            w2a[e] = kl | (kh<<16);
        }
        #pragma unroll
        for (int e4=0;e4<4;e4++){
            *(uint4*)&Ka1[key*20 + e4*4] = *(uint4*)&w1a[e4*4];
            *(uint4*)&Ka2[key*20 + e4*4] = *(uint4*)&w2a[e4*4];
        }
    } else {
        // ---- V stager: exact trunc-3 split, interleaved [vh|vm]/[vm|vh]/[vl|vh] ----
        const float4* vrow = (const float4*)(v + ((size_t)bh*LSEQ + pos)*DHD);
        float4 v0=vrow[0], v1=vrow[1], v2=vrow[2], v3=vrow[3];
        float vvv[16] = {v0.x,v0.y,v0.z,v0.w, v1.x,v1.y,v1.z,v1.w,
                         v2.x,v2.y,v2.z,v2.w, v3.x,v3.y,v3.z,v3.w};
        int kt = key >> 4, jl = key & 15;
        int base = kt*328 + jl;
        #pragma unroll
        for (int d=0;d<16;d++){
            unsigned vh_, vm_, vl_;
            split3(vvv[d], vh_, vm_, vl_);
            Va1[base + d*20] = vh_ | (vm_<<16);
            Va2[base + d*20] = vm_ | (vh_<<16);
            Va3[base + d*20] = vl_ | (vh_<<16);
        }
    }
    __syncthreads();

    int w = tid >> 6, lane = tid & 63;
    int quad = lane >> 4, col = lane & 15;

    // ---- Q A-frag: per-lane gather from global, RN-2 split, 0.25 folded ----
    int qgpos = kposS[16*w + col];
    float4 qv = *((const float4*)(qk + ((size_t)bh*LSEQ + qgpos)*DHD) + quad);
    float qx[4] = {qv.x, qv.y, qv.z, qv.w};
    FU4 QA;
    #pragma unroll
    for (int i=0;i<4;i++){
        float x = qx[i]*0.25f;
        unsigned qh = rnbf(x);
        unsigned ql = rnbf(x - bf2f(qh));
        ((unsigned*)&QA.v)[i] = qh | (ql<<16);
    }
    frag_ab qA = QA.f;

    // ---- QK^T: 8 tiles x 2 MFMA ----
    frag_c acc[8];
    #pragma unroll
    for (int nt=0; nt<8; nt++){
        FU4 B1, B2;
        B1.v = *(const uint4*)&Ka1[(nt*16+col)*20 + 4*quad];
        B2.v = *(const uint4*)&Ka2[(nt*16+col)*20 + 4*quad];
        frag_c a = {0.f,0.f,0.f,0.f};
        a = __builtin_amdgcn_mfma_f32_16x16x32_bf16(qA, B1.f, a, 0, 0, 0);
        a = __builtin_amdgcn_mfma_f32_16x16x32_bf16(qA, B2.f, a, 0, 0, 0);
        acc[nt] = a;
    }
    // self-mask: lane holds rows 16w + quad*4 + reg, key col = nt*16 + col
    int qp[4];
    #pragma unroll
    for (int reg=0; reg<4; reg++) qp[reg] = kposS[16*w + quad*4 + reg];
    #pragma unroll
    for (int nt=0; nt<8; nt++){
        int kp2 = kposS[nt*16 + col];
        #pragma unroll
        for (int reg=0; reg<4; reg++)
            if (kp2 == qp[reg]) acc[nt][reg] = -5e4f;
    }
    // ---- softmax over 128 = 8 tiles (in-lane) x 16 lanes (cols) ----
    float mx[4] = {-3.4e38f,-3.4e38f,-3.4e38f,-3.4e38f};
    #pragma unroll
    for (int nt=0; nt<8; nt++)
        #pragma unroll
        for (int reg=0; reg<4; reg++) mx[reg] = fmaxf(mx[reg], acc[nt][reg]);
    #pragma unroll
    for (int reg=0; reg<4; reg++){
        float m2 = mx[reg];
        m2 = fmaxf(m2, __shfl_xor(m2, 1)); m2 = fmaxf(m2, __shfl_xor(m2, 2));
        m2 = fmaxf(m2, __shfl_xor(m2, 4)); m2 = fmaxf(m2, __shfl_xor(m2, 8));
        mx[reg] = m2;
    }
    float sm2[4] = {0.f,0.f,0.f,0.f};
    #pragma unroll
    for (int nt=0; nt<8; nt++)
        #pragma unroll
        for (int reg=0; reg<4; reg++){
            float e = __expf(acc[nt][reg] - mx[reg]);
            acc[nt][reg] = e; sm2[reg] += e;
        }
    #pragma unroll
    for (int reg=0; reg<4; reg++){
        float s2 = sm2[reg];
        s2 += __shfl_xor(s2, 1); s2 += __shfl_xor(s2, 2);
        s2 += __shfl_xor(s2, 4); s2 += __shfl_xor(s2, 8);
        sm2[reg] = s2;
    }
    float invs[4];
    #pragma unroll
    for (int reg=0; reg<4; reg++) invs[reg] = 1.f / sm2[reg];
    if (col == 0) {
        #pragma unroll
        for (int reg=0; reg<4; reg++)
            slog[((size_t)bh*NHASH + h)*LSEQ + qp[reg]] = mx[reg] + __logf(sm2[reg]);
    }

    // ---- PV: 4 passes x (2 tiles x 3 MFMA) through aliased P buffer ----
    frag_c o = {0.f,0.f,0.f,0.f};
    __syncthreads();   // Ka/Qa region dead; safe to overwrite with Pa
    #pragma unroll
    for (int pass=0; pass<4; pass++){
        #pragma unroll
        for (int t2=0; t2<2; t2++){
            int nt = pass*2 + t2;
            #pragma unroll
            for (int reg=0; reg<4; reg++){
                float p = acc[nt][reg] * invs[reg];
                unsigned ph_, pm_, pl_;
                split3(p, ph_, pm_, pl_);
                int idx = t2*1280 + (16*w + 4*quad + reg)*20 + col;
                Pa1[idx] = ph_ | (pm_<<16);
                Pa2[idx] = ph_ | (pl_<<16);
            }
        }
        __syncthreads();
        #pragma unroll
        for (int t2=0; t2<2; t2++){
            int ktg = pass*2 + t2;
            FU4 A1, A2, B1, B2, B3;
            int pidx = t2*1280 + (16*w + col)*20 + 4*quad;
            A1.v = *(const uint4*)&Pa1[pidx];
            A2.v = *(const uint4*)&Pa2[pidx];
            int vidx = ktg*328 + col*20 + 4*quad;
            B1.v = *(const uint4*)&Va1[vidx];
            B2.v = *(const uint4*)&Va2[vidx];
            B3.v = *(const uint4*)&Va3[vidx];
            o = __builtin_amdgcn_mfma_f32_16x16x32_bf16(A1.f, B1.f, o, 0, 0, 0);
            o = __builtin_amdgcn_mfma_f32_16x16x32_bf16(A1.f, B2.f, o, 0, 0, 0);
            o = __builtin_amdgcn_mfma_f32_16x16x32_bf16(A2.f, B3.f, o, 0, 0, 0);
        }
        if (pass < 3) __syncthreads();
    }
    size_t obase = ((size_t)bh*NHASH + h)*LSEQ;
    #pragma unroll
    for (int reg=0; reg<4; reg++)
        o_hash[(obase + qp[reg])*DHD + col] = o[reg];
}

// ---------------- hash-round combine + output proj + residual into x1 ----------------
// block = 64 tokens of one batch; grid 320
__global__ __launch_bounds__(256) void k_combine(
    const float* __restrict__ o_hash, const float* __restrict__ slog,
    const float* __restrict__ wo_w, const float* __restrict__ wo_b, float* __restrict__ x1)
{
    __shared__ float att[64][65];
    int tid = threadIdx.x;
    int b  = blockIdx.x / 20;
    int t0 = (blockIdx.x % 20) * 64;
    int ttk = tid >> 2, head = tid & 3;
    int t = t0 + ttk;
    int bh = b*NHEADS + head;
    float sl[4];
    for (int nh=0;nh<4;nh++) sl[nh] = slog[((size_t)bh*NHASH + nh)*LSEQ + t];
    float mx = fmaxf(fmaxf(sl[0],sl[1]), fmaxf(sl[2],sl[3]));
    float wsum = 0.f; float wv[4];
    for (int nh=0;nh<4;nh++){ wv[nh] = __expf(sl[nh]-mx); wsum += wv[nh]; }
    float invs = 1.f/wsum;
    float a[16];
    for (int d=0;d<16;d++) a[d]=0.f;
    for (int nh=0;nh<4;nh++){
        const float4* orow = (const float4*)(o_hash + (((size_t)bh*NHASH + nh)*LSEQ + t)*DHD);
        float wn = wv[nh]*invs;
        float4 A=orow[0], B=orow[1], C=orow[2], Dq=orow[3];
        a[0]+=wn*A.x;  a[1]+=wn*A.y;  a[2]+=wn*A.z;  a[3]+=wn*A.w;
        a[4]+=wn*B.x;  a[5]+=wn*B.y;  a[6]+=wn*B.z;  a[7]+=wn*B.w;
        a[8]+=wn*C.x;  a[9]+=wn*C.y;  a[10]+=wn*C.z; a[11]+=wn*C.w;
        a[12]+=wn*Dq.x;a[13]+=wn*Dq.y;a[14]+=wn*Dq.z;a[15]+=wn*Dq.w;
    }
    for (int d=0;d<16;d++) att[ttk][head*16+d] = a[d];
    __syncthreads();
    int cg = tid & 15, tg = tid >> 4;
    int c0 = cg*4, tl0 = tg*4;
    float acc[4][4];
    for (int i=0;i<4;i++) for (int j=0;j<4;j++) acc[i][j]=0.f;
    for (int f=0; f<64; f++){
        float4 w4 = *(const float4*)&wo_w[f*64 + c0];
        float xv[4];
        for (int i=0;i<4;i++) xv[i] = att[tl0+i][f];
        for (int i=0;i<4;i++){
            acc[i][0]+=xv[i]*w4.x; acc[i][1]+=xv[i]*w4.y;
            acc[i][2]+=xv[i]*w4.z; acc[i][3]+=xv[i]*w4.w;
        }
    }
    float4 bb = *(const float4*)&wo_b[c0];
    for (int i=0;i<4;i++){
        size_t idx = ((size_t)b*LSEQ + (t0 + tl0 + i))*DM + c0;
        float4 cur = *(float4*)&x1[idx];
        cur.x += acc[i][0]+bb.x; cur.y += acc[i][1]+bb.y;
        cur.z += acc[i][2]+bb.z; cur.w += acc[i][3]+bb.w;
        *(float4*)&x1[idx] = cur;
    }
}

// ---------------- LN2 + W1 + gelu -> mid ----------------
// block = 32 tokens; grid 640
__global__ __launch_bounds__(256) void k_ff1(
    const float* __restrict__ x1, const float* __restrict__ g, const float* __restrict__ bta,
    const float* __restrict__ w1, const float* __restrict__ b1, float* __restrict__ mid)
{
    __shared__ float w1s[16*256];
    __shared__ float xln[32][65];
    __shared__ float ps[32][8], pq[32][8];
    int tid = threadIdx.x;
    int tbase = blockIdx.x * 32;
    int r = tid >> 3, qq = tid & 7;
    const float* xr = x1 + (size_t)(tbase + r)*DM;
    float vals[8]; float s = 0.f, ss = 0.f;
    for (int i=0;i<8;i++){ float vv = xr[qq*8+i]; vals[i]=vv; s+=vv; ss+=vv*vv; }
    ps[r][qq]=s; pq[r][qq]=ss;
    __syncthreads();
    float m=0.f, vr=0.f;
    for (int k2=0;k2<8;k2++){ m+=ps[r][k2]; vr+=pq[r][k2]; }
    m *= (1.f/64.f); vr = vr*(1.f/64.f) - m*m;
    float rstd = 1.f/sqrtf(vr+1e-5f);
    for (int i=0;i<8;i++){ int cidx=qq*8+i; xln[r][cidx] = (vals[i]-m)*rstd*g[cidx]+bta[cidx]; }
    float acc[4][8];
    for (int i=0;i<4;i++) for (int k2=0;k2<8;k2++) acc[i][k2]=0.f;
    int tg = tid >> 5;      // 8 groups of 4 tokens
    int cg = tid & 31;      // out col = cg + 32*k2
    int tl0 = tg*4;
    for (int fc = 0; fc < 4; fc++) {
        __syncthreads();
        for (int j = tid; j < 1024; j += 256)
            *(float4*)&w1s[j*4] = *(const float4*)&w1[fc*4096 + j*4];
        __syncthreads();
        for (int fl = 0; fl < 16; fl++) {
            int f = fc*16 + fl;
            float xv[4];
            for (int i=0;i<4;i++) xv[i] = xln[tl0+i][f];
            for (int k2=0;k2<8;k2++) {
                float wvv = w1s[fl*256 + cg + 32*k2];
                for (int i=0;i<4;i++) acc[i][k2] += xv[i]*wvv;
            }
        }
    }
    for (int k2=0;k2<8;k2++){
        int cidx = cg + 32*k2;
        float bb = b1[cidx];
        for (int i=0;i<4;i++){
            float xx = acc[i][k2] + bb;
            float ge = 0.5f*xx*(1.f + erff(xx*0.70710678118654752f));
            mid[(size_t)(tbase + tl0 + i)*FFD + cidx] = ge;
        }
    }
}

// ---------------- mid @ W2 + b2 -> residual into x2 ----------------
// block = 64 tokens; grid 320
__global__ __launch_bounds__(256) void k_ff2(
    const float* __restrict__ mid, const float* __restrict__ w2, const float* __restrict__ b2,
    float* __restrict__ x2)
{
    __shared__ float mids[64][65];
    int tid = threadIdx.x;
    int tbase = blockIdx.x * 64;
    int tg = tid >> 4, cg = tid & 15;
    int tl0 = tg*4, c0 = cg*4;
    float acc[4][4];
    for (int i=0;i<4;i++) for (int j=0;j<4;j++) acc[i][j]=0.f;
    for (int fc = 0; fc < 4; fc++) {
        __syncthreads();
        for (int j = tid; j < 1024; j += 256) {
            int row = j >> 4; int col4 = (j & 15) * 4;
            float4 vv = *(const float4*)&mid[(size_t)(tbase+row)*FFD + fc*64 + col4];
            mids[row][col4+0]=vv.x; mids[row][col4+1]=vv.y;
            mids[row][col4+2]=vv.z; mids[row][col4+3]=vv.w;
        }
        __syncthreads();
        for (int fl = 0; fl < 64; fl++) {
            float4 wv4 = *(const float4*)&w2[(fc*64+fl)*64 + c0];
            float mv[4];
            for (int i=0;i<4;i++) mv[i] = mids[tl0+i][fl];
            for (int i=0;i<4;i++){
                acc[i][0]+=mv[i]*wv4.x; acc[i][1]+=mv[i]*wv4.y;
                acc[i][2]+=mv[i]*wv4.z; acc[i][3]+=mv[i]*wv4.w;
            }
        }
    }
    float4 bb = *(const float4*)&b2[c0];
    for (int i=0;i<4;i++){
        size_t idx = ((size_t)(tbase + tl0 + i))*DM + c0;
        float4 cur = *(float4*)&x2[idx];
        cur.x += acc[i][0]+bb.x; cur.y += acc[i][1]+bb.y;
        cur.z += acc[i][2]+bb.z; cur.w += acc[i][3]+bb.w;
        *(float4*)&x2[idx] = cur;
    }
}

// ---------------- output proj: y = 0.5*(x1+x2) @ out_w + out_b, crop to 1250 ----------------
__global__ __launch_bounds__(256) void k_out(
    const float* __restrict__ x1, const float* __restrict__ x2,
    const float* __restrict__ out_w, const float* __restrict__ out_b, float* __restrict__ y)
{
    int idx = blockIdx.x * 256 + threadIdx.x;
    if (idx >= NBATCH * L0SEQ) return;
    int b = idx / L0SEQ, t = idx % L0SEQ;
    const float* r1 = x1 + ((size_t)b*LSEQ + t)*DM;
    const float* r2 = x2 + ((size_t)b*LSEQ + t)*DM;
    float s = 0.f;
    for (int d = 0; d < DM; d++) s += (r1[d]+r2[d])*0.5f*out_w[d];
    y[idx] = s + out_b[0];
}

extern "C" void kernel_launch(void* const* d_in, const int* in_sizes, int n_in,
                              void* d_out, int out_size, void* d_ws, size_t ws_size,
                              hipStream_t stream)
{
    const float* wave  = (const float*)d_in[0];
    const float* in_w  = (const float*)d_in[1];
    const float* in_b  = (const float*)d_in[2];
    const float* ln1_g = (const float*)d_in[3];
    const float* ln1_b = (const float*)d_in[4];
    const float* wqk   = (const float*)d_in[5];
    const float* wv    = (const float*)d_in[6];
    const float* wo_w  = (const float*)d_in[7];
    const float* wo_b  = (const float*)d_in[8];
    const float* rot   = (const float*)d_in[9];
    const float* ln2_g = (const float*)d_in[10];
    const float* ln2_b = (const float*)d_in[11];
    const float* w1    = (const float*)d_in[12];
    const float* b1    = (const float*)d_in[13];
    const float* w2    = (const float*)d_in[14];
    const float* b2    = (const float*)d_in[15];
    const float* out_w = (const float*)d_in[16];
    const float* out_b = (const float*)d_in[17];
    float* y = (float*)d_out;

    float* ws = (float*)d_ws;
    float* x1     = ws;                  // XSZ
    float* x2     = x1 + XSZ;            // XSZ
    float* qkb    = x2 + XSZ;            // QKSZ
    float* vb     = qkb + QKSZ;          // QKSZ
    float* o_hash = vb + QKSZ;           // OHSZ
    float* slogb  = o_hash + OHSZ;       // SLSZ
    int* buckets  = (int*)(slogb + SLSZ); // SLSZ ints
    int* sorted   = buckets + SLSZ;      // SLSZ ints
    float* mid    = o_hash;              // reuse (disjoint lifetime within a layer)

    k_embed<<<XSZ/256, 256, 0, stream>>>(wave, in_w, in_b, x1, x2);
    for (int layer = 0; layer < 4; layer++) {
        k_qkv<<<320, 256, 0, stream>>>(x2, ln1_g + layer*64, ln1_b + layer*64,
                                       wqk + layer*4096, wv + layer*4096, rot + layer*640,
                                       qkb, vb, buckets);
        k_sort<<<256, 64, 0, stream>>>(buckets, sorted);
        k_attn<<<NBH*NCHUNK, 256, 0, stream>>>(qkb, vb, sorted, o_hash, slogb);
        k_combine<<<320, 256, 0, stream>>>(o_hash, slogb, wo_w + layer*4096, wo_b + layer*64, x1);
        k_ff1<<<640, 256, 0, stream>>>(x1, ln2_g + layer*64, ln2_b + layer*64,
                                       w1 + layer*16384, b1 + layer*256, mid);
        k_ff2<<<320, 256, 0, stream>>>(mid, w2 + layer*16384, b2 + layer*64, x2);
    }
    k_out<<<(NBATCH*L0SEQ + 255)/256, 256, 0, stream>>>(x1, x2, out_w, out_b, y);
}

// Round 7
// 673.249 us; speedup vs baseline: 1.2287x; 1.0706x over previous
//
#include <hip/hip_runtime.h>
#include <math.h>

#define LSEQ 1280
#define L0SEQ 1250
#define DM 64
#define NHEADS 4
#define DHD 16
#define NHASH 4
#define NBUK 20
#define NCHUNK 80
#define FFD 256
#define NBATCH 16
#define NBH 64

#define XSZ (NBATCH*LSEQ*DM)        // 1310720
#define QKSZ (NBH*LSEQ*DHD)         // 1310720
#define OHSZ (NBH*NHASH*LSEQ*DHD)   // 5242880
#define SLSZ (NBH*NHASH*LSEQ)       // 327680

typedef __attribute__((ext_vector_type(8))) short frag_ab;   // 8 bf16
typedef __attribute__((ext_vector_type(4))) float frag_c;    // 4 fp32

union FU4 { uint4 v; frag_ab f; };

// round-to-nearest bf16 (returns low 16 bits)
__device__ __forceinline__ unsigned rnbf(float x){
    unsigned b = __float_as_uint(x);
    return (b + 0x7fffu + ((b >> 16) & 1u)) >> 16;
}
__device__ __forceinline__ float bf2f(unsigned h){ return __uint_as_float(h << 16); }

// exact triple split (truncation): x = h + m + l
__device__ __forceinline__ void split3(float x, unsigned& h, unsigned& m, unsigned& l){
    unsigned bx = __float_as_uint(x);
    h = bx >> 16;
    float r = x - __uint_as_float(bx & 0xffff0000u);
    unsigned br = __float_as_uint(r);
    m = br >> 16;
    float r2 = r - __uint_as_float(br & 0xffff0000u);
    l = __float_as_uint(r2) >> 16;
}

// ---------------- embed: x = pad(wave^T) @ in_w + in_b ----------------
__global__ __launch_bounds__(256) void k_embed(
    const float* __restrict__ wave, const float* __restrict__ in_w,
    const float* __restrict__ in_b, float* __restrict__ x1, float* __restrict__ x2)
{
    int idx = blockIdx.x * 256 + threadIdx.x;   // over B*L*D
    int d = idx & 63;
    int t = idx >> 6;
    int b = t / LSEQ;
    int tt = t % LSEQ;
    float v0 = 0.f, v1 = 0.f;
    if (tt < L0SEQ) {
        v0 = wave[(size_t)(b*2+0)*L0SEQ + tt];
        v1 = wave[(size_t)(b*2+1)*L0SEQ + tt];
    }
    float x = v0 * in_w[d] + v1 * in_w[64 + d] + in_b[d];
    x1[idx] = x;
    x2[idx] = x;
}

// ---------------- weight pre-split into MFMA-B layout (trunc-3, k-slot paired) ----------------
// For a K x N matrix: u32 word index = ((kt*(N/16)+nt)*16 + nc)*16 + kc
// arrays: B1 = h|m<<16, B2 = m|h<<16, B3 = l|h<<16 at base, base+KN, base+2*KN
__global__ __launch_bounds__(256) void k_prep(
    const float* __restrict__ wo_w, const float* __restrict__ w1,
    const float* __restrict__ w2, unsigned* __restrict__ wsplit)
{
    int gid = blockIdx.x * 256 + threadIdx.x;
    if (gid >= 4*36864) return;
    int l = gid / 36864;
    int r = gid % 36864;
    float src; unsigned* dst; int idx; int stride;
    if (r < 4096) {                 // wo: K=64, N=64
        int k = r >> 6, n = r & 63;
        src = wo_w[l*4096 + k*64 + n];
        dst = wsplit + l*12288;
        idx = (((k>>4)*4 + (n>>4))*16 + (n&15))*16 + (k&15);
        stride = 4096;
    } else if (r < 20480) {         // w1: K=64, N=256
        int rr = r - 4096;
        int k = rr >> 8, n = rr & 255;
        src = w1[l*16384 + k*256 + n];
        dst = wsplit + 49152 + l*49152;
        idx = (((k>>4)*16 + (n>>4))*16 + (n&15))*16 + (k&15);
        stride = 16384;
    } else {                        // w2: K=256, N=64
        int rr = r - 20480;
        int k = rr >> 6, n = rr & 63;
        src = w2[l*16384 + k*64 + n];
        dst = wsplit + 245760 + l*49152;
        idx = (((k>>4)*4 + (n>>4))*16 + (n&15))*16 + (k&15);
        stride = 16384;
    }
    unsigned h, m, lo;
    split3(src, h, m, lo);
    dst[idx]            = h | (m<<16);
    dst[idx + stride]   = m | (h<<16);
    dst[idx + 2*stride] = lo | (h<<16);
}

// ---------------- LN + QK/V projection + LSH bucketing ----------------
// block = 64 tokens of one batch; grid 320
__global__ __launch_bounds__(256) void k_qkv(
    const float* __restrict__ x2, const float* __restrict__ g, const float* __restrict__ bta,
    const float* __restrict__ wqk, const float* __restrict__ wv, const float* __restrict__ rot,
    float* __restrict__ qk, float* __restrict__ v, int* __restrict__ buckets)
{
    __shared__ float xln[64][65];
    __shared__ float qkt[64][65];
    __shared__ float rots[640];
    __shared__ float psum[64][4];
    __shared__ float psq[64][4];
    int tid = threadIdx.x;
    int b  = blockIdx.x / 20;
    int t0 = (blockIdx.x % 20) * 64;
    const float* xbase = x2 + (size_t)(b*LSEQ + t0)*DM;
    int r = tid >> 2, qq = tid & 3;
    float vals[16];
    float s = 0.f, ss = 0.f;
    for (int i = 0; i < 16; i++) {
        float vv = xbase[r*DM + qq*16 + i];
        vals[i] = vv; s += vv; ss += vv*vv;
    }
    psum[r][qq] = s; psq[r][qq] = ss;
    for (int i = tid; i < 640; i += 256) rots[i] = rot[i];
    __syncthreads();
    float m  = (psum[r][0]+psum[r][1]+psum[r][2]+psum[r][3]) * (1.f/64.f);
    float vr = (psq[r][0]+psq[r][1]+psq[r][2]+psq[r][3]) * (1.f/64.f) - m*m;
    float rstd = 1.f / sqrtf(vr + 1e-5f);
    for (int i = 0; i < 16; i++) {
        int c = qq*16 + i;
        xln[r][c] = (vals[i]-m)*rstd*g[c] + bta[c];
    }
    __syncthreads();
    // matmuls: thread tile = 4 tokens x 4 cols
    int cg = tid & 15, tg = tid >> 4;
    int c0 = cg*4, tl0 = tg*4;
    float aq[4][4], av[4][4];
    for (int i=0;i<4;i++) for (int j=0;j<4;j++){ aq[i][j]=0.f; av[i][j]=0.f; }
    for (int f = 0; f < 64; f++) {
        float4 wq4 = *(const float4*)&wqk[f*64 + c0];
        float4 wv4 = *(const float4*)&wv [f*64 + c0];
        float xv[4];
        for (int i=0;i<4;i++) xv[i] = xln[tl0+i][f];
        for (int i=0;i<4;i++) {
            aq[i][0] += xv[i]*wq4.x; aq[i][1] += xv[i]*wq4.y;
            aq[i][2] += xv[i]*wq4.z; aq[i][3] += xv[i]*wq4.w;
            av[i][0] += xv[i]*wv4.x; av[i][1] += xv[i]*wv4.y;
            av[i][2] += xv[i]*wv4.z; av[i][3] += xv[i]*wv4.w;
        }
    }
    int head = c0 >> 4;
    int dh0  = c0 & 15;
    for (int i=0;i<4;i++) {
        int t = t0 + tl0 + i;
        float4 q4; q4.x=aq[i][0]; q4.y=aq[i][1]; q4.z=aq[i][2]; q4.w=aq[i][3];
        float4 v4; v4.x=av[i][0]; v4.y=av[i][1]; v4.z=av[i][2]; v4.w=av[i][3];
        *(float4*)&qk[((size_t)(b*NHEADS+head)*LSEQ + t)*DHD + dh0] = q4;
        *(float4*)&v [((size_t)(b*NHEADS+head)*LSEQ + t)*DHD + dh0] = v4;
        qkt[tl0+i][c0+0] = aq[i][0]; qkt[tl0+i][c0+1] = aq[i][1];
        qkt[tl0+i][c0+2] = aq[i][2]; qkt[tl0+i][c0+3] = aq[i][3];
    }
    __syncthreads();
    // buckets: thread = (token, head)
    int ttk = tid >> 2, hh = tid & 3;
    float qf[16];
    for (int f=0; f<16; f++) qf[f] = qkt[ttk][hh*16+f];
    int tglob = t0 + ttk;
    for (int nh = 0; nh < NHASH; nh++) {
        float rv[10];
        for (int i=0;i<10;i++) {
            float acc = 0.f;
            for (int f=0; f<16; f++) acc += qf[f]*rots[(f*NHASH+nh)*10 + i];
            rv[i] = acc;
        }
        float best = rv[0]; int bi = 0;
        for (int i=1;i<10;i++) if (rv[i] > best) { best = rv[i]; bi = i; }
        for (int i=0;i<10;i++) if (-rv[i] > best) { best = -rv[i]; bi = 10+i; }
        buckets[((size_t)(b*NHEADS+hh)*NHASH + nh)*LSEQ + tglob] = bi;
    }
}

// ---------------- counting sort per (bh, hash): stable, ballot-ranked ----------------
// one wave per (bh,hash) group; grid 256, block 64
__global__ __launch_bounds__(64) void k_sort(
    const int* __restrict__ buckets, int* __restrict__ sorted)
{
    __shared__ int hist[20];
    __shared__ int startl[20];
    int lane = threadIdx.x;
    int gidx = blockIdx.x;
    const int* bk = buckets + (size_t)gidx * LSEQ;
    int* dst = sorted + (size_t)gidx * LSEQ;
    if (lane < 20) hist[lane] = 0;
    __syncthreads();
    int myb[20];
    for (int ch = 0; ch < 20; ch++) {
        myb[ch] = bk[ch*64 + lane];
        atomicAdd(&hist[myb[ch]], 1);
    }
    __syncthreads();
    if (lane == 0) {
        int acc = 0;
        for (int b2 = 0; b2 < 20; b2++) { startl[b2] = acc; acc += hist[b2]; }
    }
    __syncthreads();
    unsigned long long below = (lane == 63) ? 0x7fffffffffffffffull
                                            : ((1ull << lane) - 1ull);
    for (int ch = 0; ch < 20; ch++) {
        int bv = myb[ch];
        unsigned long long mymask = 0, ownmask = 0;
        #pragma unroll
        for (int b2 = 0; b2 < 20; b2++) {
            unsigned long long m2 = __ballot(bv == b2);
            if (b2 == bv)   mymask  = m2;
            if (b2 == lane) ownmask = m2;
        }
        int rank = __popcll(mymask & below);
        int base = startl[bv];
        dst[base + rank] = ch*64 + lane;
        __syncthreads();
        if (lane < 20) startl[lane] += __popcll(ownmask);
        __syncthreads();
    }
}

// ---------------- chunked attention (round-6 structure, unchanged) ----------------
__global__ __launch_bounds__(256) void k_attn(
    const float* __restrict__ qk, const float* __restrict__ v,
    const int* __restrict__ sorted, float* __restrict__ o_hash, float* __restrict__ slog)
{
    __shared__ __align__(16) unsigned SMEM[13120];
    unsigned* Va1 = SMEM;
    unsigned* Va2 = SMEM + 2624;
    unsigned* Va3 = SMEM + 5248;
    unsigned* Ka1 = SMEM + 7872;
    unsigned* Ka2 = SMEM + 10432;
    unsigned* Pa1 = SMEM + 7872;
    unsigned* Pa2 = SMEM + 10432;
    int* kposS = (int*)(SMEM + 12992);

    int tid = threadIdx.x;
    int bh = blockIdx.x / NCHUNK;
    int c  = blockIdx.x % NCHUNK;
    int h  = c / NBUK, cc = c % NBUK;
    int cp = (c + NCHUNK - 1) % NCHUNK;
    int hp = cp / NBUK, ccp = cp % NBUK;

    int key = tid & 127;
    int pos = (key < 64)
        ? sorted[((size_t)bh*NHASH + h)*LSEQ + cc*64 + key]
        : sorted[((size_t)bh*NHASH + hp)*LSEQ + ccp*64 + (key-64)];
    if (tid < 128) {
        kposS[key] = pos;
        const float4* qrow = (const float4*)(qk + ((size_t)bh*LSEQ + pos)*DHD);
        float4 r0=qrow[0], r1=qrow[1], r2=qrow[2], r3=qrow[3];
        float rr[16] = {r0.x,r0.y,r0.z,r0.w, r1.x,r1.y,r1.z,r1.w,
                        r2.x,r2.y,r2.z,r2.w, r3.x,r3.y,r3.z,r3.w};
        float nsq = 0.f;
        #pragma unroll
        for (int e=0;e<16;e++) nsq += rr[e]*rr[e];
        float inv = 1.f / fmaxf(sqrtf(nsq), 1e-12f);
        unsigned w1a[16], w2a[16];
        #pragma unroll
        for (int e=0;e<16;e++){
            float x = rr[e]*inv;
            unsigned kh = rnbf(x);
            unsigned kl = rnbf(x - bf2f(kh));
            w1a[e] = kh | (kl<<16);
            w2a[e] = kl | (kh<<16);
        }
        #pragma unroll
        for (int e4=0;e4<4;e4++){
            *(uint4*)&Ka1[key*20 + e4*4] = *(uint4*)&w1a[e4*4];
            *(uint4*)&Ka2[key*20 + e4*4] = *(uint4*)&w2a[e4*4];
        }
    } else {
        const float4* vrow = (const float4*)(v + ((size_t)bh*LSEQ + pos)*DHD);
        float4 v0=vrow[0], v1=vrow[1], v2=vrow[2], v3=vrow[3];
        float vvv[16] = {v0.x,v0.y,v0.z,v0.w, v1.x,v1.y,v1.z,v1.w,
                         v2.x,v2.y,v2.z,v2.w, v3.x,v3.y,v3.z,v3.w};
        int kt = key >> 4, jl = key & 15;
        int base = kt*328 + jl;
        #pragma unroll
        for (int d=0;d<16;d++){
            unsigned vh_, vm_, vl_;
            split3(vvv[d], vh_, vm_, vl_);
            Va1[base + d*20] = vh_ | (vm_<<16);
            Va2[base + d*20] = vm_ | (vh_<<16);
            Va3[base + d*20] = vl_ | (vh_<<16);
        }
    }
    __syncthreads();

    int w = tid >> 6, lane = tid & 63;
    int quad = lane >> 4, col = lane & 15;

    int qgpos = kposS[16*w + col];
    float4 qv = *((const float4*)(qk + ((size_t)bh*LSEQ + qgpos)*DHD) + quad);
    float qx[4] = {qv.x, qv.y, qv.z, qv.w};
    FU4 QA;
    #pragma unroll
    for (int i=0;i<4;i++){
        float x = qx[i]*0.25f;
        unsigned qh = rnbf(x);
        unsigned ql = rnbf(x - bf2f(qh));
        ((unsigned*)&QA.v)[i] = qh | (ql<<16);
    }
    frag_ab qA = QA.f;

    frag_c acc[8];
    #pragma unroll
    for (int nt=0; nt<8; nt++){
        FU4 B1, B2;
        B1.v = *(const uint4*)&Ka1[(nt*16+col)*20 + 4*quad];
        B2.v = *(const uint4*)&Ka2[(nt*16+col)*20 + 4*quad];
        frag_c a = {0.f,0.f,0.f,0.f};
        a = __builtin_amdgcn_mfma_f32_16x16x32_bf16(qA, B1.f, a, 0, 0, 0);
        a = __builtin_amdgcn_mfma_f32_16x16x32_bf16(qA, B2.f, a, 0, 0, 0);
        acc[nt] = a;
    }
    int qp[4];
    #pragma unroll
    for (int reg=0; reg<4; reg++) qp[reg] = kposS[16*w + quad*4 + reg];
    #pragma unroll
    for (int nt=0; nt<8; nt++){
        int kp2 = kposS[nt*16 + col];
        #pragma unroll
        for (int reg=0; reg<4; reg++)
            if (kp2 == qp[reg]) acc[nt][reg] = -5e4f;
    }
    float mx[4] = {-3.4e38f,-3.4e38f,-3.4e38f,-3.4e38f};
    #pragma unroll
    for (int nt=0; nt<8; nt++)
        #pragma unroll
        for (int reg=0; reg<4; reg++) mx[reg] = fmaxf(mx[reg], acc[nt][reg]);
    #pragma unroll
    for (int reg=0; reg<4; reg++){
        float m2 = mx[reg];
        m2 = fmaxf(m2, __shfl_xor(m2, 1)); m2 = fmaxf(m2, __shfl_xor(m2, 2));
        m2 = fmaxf(m2, __shfl_xor(m2, 4)); m2 = fmaxf(m2, __shfl_xor(m2, 8));
        mx[reg] = m2;
    }
    float sm2[4] = {0.f,0.f,0.f,0.f};
    #pragma unroll
    for (int nt=0; nt<8; nt++)
        #pragma unroll
        for (int reg=0; reg<4; reg++){
            float e = __expf(acc[nt][reg] - mx[reg]);
            acc[nt][reg] = e; sm2[reg] += e;
        }
    #pragma unroll
    for (int reg=0; reg<4; reg++){
        float s2 = sm2[reg];
        s2 += __shfl_xor(s2, 1); s2 += __shfl_xor(s2, 2);
        s2 += __shfl_xor(s2, 4); s2 += __shfl_xor(s2, 8);
        sm2[reg] = s2;
    }
    float invs[4];
    #pragma unroll
    for (int reg=0; reg<4; reg++) invs[reg] = 1.f / sm2[reg];
    if (col == 0) {
        #pragma unroll
        for (int reg=0; reg<4; reg++)
            slog[((size_t)bh*NHASH + h)*LSEQ + qp[reg]] = mx[reg] + __logf(sm2[reg]);
    }

    frag_c o = {0.f,0.f,0.f,0.f};
    __syncthreads();
    #pragma unroll
    for (int pass=0; pass<4; pass++){
        #pragma unroll
        for (int t2=0; t2<2; t2++){
            int nt = pass*2 + t2;
            #pragma unroll
            for (int reg=0; reg<4; reg++){
                float p = acc[nt][reg] * invs[reg];
                unsigned ph_, pm_, pl_;
                split3(p, ph_, pm_, pl_);
                int idx = t2*1280 + (16*w + 4*quad + reg)*20 + col;
                Pa1[idx] = ph_ | (pm_<<16);
                Pa2[idx] = ph_ | (pl_<<16);
            }
        }
        __syncthreads();
        #pragma unroll
        for (int t2=0; t2<2; t2++){
            int ktg = pass*2 + t2;
            FU4 A1, A2, B1, B2, B3;
            int pidx = t2*1280 + (16*w + col)*20 + 4*quad;
            A1.v = *(const uint4*)&Pa1[pidx];
            A2.v = *(const uint4*)&Pa2[pidx];
            int vidx = ktg*328 + col*20 + 4*quad;
            B1.v = *(const uint4*)&Va1[vidx];
            B2.v = *(const uint4*)&Va2[vidx];
            B3.v = *(const uint4*)&Va3[vidx];
            o = __builtin_amdgcn_mfma_f32_16x16x32_bf16(A1.f, B1.f, o, 0, 0, 0);
            o = __builtin_amdgcn_mfma_f32_16x16x32_bf16(A1.f, B2.f, o, 0, 0, 0);
            o = __builtin_amdgcn_mfma_f32_16x16x32_bf16(A2.f, B3.f, o, 0, 0, 0);
        }
        if (pass < 3) __syncthreads();
    }
    size_t obase = ((size_t)bh*NHASH + h)*LSEQ;
    #pragma unroll
    for (int reg=0; reg<4; reg++)
        o_hash[(obase + qp[reg])*DHD + col] = o[reg];
}

// ---------------- fused tail: combine + WO + residual + LN2 + W1 + gelu + W2 + residual ----------------
// block = 64 tokens of one batch; grid 320, 4 waves; wave w owns token rows [16w,16w+16).
// MFMA trunc-3 everywhere; weights pre-split (k_prep) read from global (L2).
// LDS: xln A-arrays + gmid A-arrays, XOR-swizzled stride 64 (word ^= (row&7)<<2). No __syncthreads.
__global__ __launch_bounds__(256) void k_tail(
    const float* __restrict__ o_hash, const float* __restrict__ slog,
    const unsigned* __restrict__ wo_s, const float* __restrict__ wo_b,
    const float* __restrict__ g2, const float* __restrict__ b2t,
    const unsigned* __restrict__ w1_s, const float* __restrict__ b1,
    const unsigned* __restrict__ w2_s, const float* __restrict__ b2f,
    float* __restrict__ x1, float* __restrict__ x2)
{
    __shared__ unsigned SM[16384];      // 64 KB: xA1, xA2, gA1, gA2 (4096 each)
    unsigned* xA1 = SM;
    unsigned* xA2 = SM + 4096;
    unsigned* gA1 = SM + 8192;
    unsigned* gA2 = SM + 12288;

    int tid = threadIdx.x;
    int b  = blockIdx.x / 20;
    int t0 = (blockIdx.x % 20) * 64;
    int w = tid >> 6, lane = tid & 63;
    int quad = lane >> 4, col = lane & 15;
    int t = t0 + 16*w + col;            // this lane's A-row token

    // ---- phase 0: combine across hash rounds, in-register A-frags for WO ----
    // lane needs att[t][d] for d = kt*16 + quad*4 + i  (head = kt)
    FU4 aA1[4], aA2[4];
    #pragma unroll
    for (int kt=0; kt<4; kt++){
        int bh = b*NHEADS + kt;
        float sl[4];
        #pragma unroll
        for (int nh=0; nh<4; nh++) sl[nh] = slog[((size_t)bh*NHASH + nh)*LSEQ + t];
        float mx = fmaxf(fmaxf(sl[0],sl[1]), fmaxf(sl[2],sl[3]));
        float wgt[4]; float wsum = 0.f;
        #pragma unroll
        for (int nh=0; nh<4; nh++){ wgt[nh] = __expf(sl[nh]-mx); wsum += wgt[nh]; }
        float iv = 1.f/wsum;
        float a4[4] = {0.f,0.f,0.f,0.f};
        #pragma unroll
        for (int nh=0; nh<4; nh++){
            float4 oh = *(const float4*)&o_hash[(((size_t)bh*NHASH + nh)*LSEQ + t)*DHD + quad*4];
            float wn = wgt[nh]*iv;
            a4[0] += wn*oh.x; a4[1] += wn*oh.y; a4[2] += wn*oh.z; a4[3] += wn*oh.w;
        }
        #pragma unroll
        for (int i=0;i<4;i++){
            unsigned h_, m_, l_;
            split3(a4[i], h_, m_, l_);
            ((unsigned*)&aA1[kt].v)[i] = h_ | (m_<<16);
            ((unsigned*)&aA2[kt].v)[i] = h_ | (l_<<16);
        }
    }

    // ---- phase 1: WO MFMA + x1 residual + LN2, write xln A-arrays (same-wave rows only) ----
    frag_c awo[4];
    #pragma unroll
    for (int nt=0; nt<4; nt++){
        frag_c a = {0.f,0.f,0.f,0.f};
        #pragma unroll
        for (int kt=0; kt<4; kt++){
            FU4 B1, B2, B3;
            int bidx = ((kt*4 + nt)*16 + col)*16 + quad*4;
            B1.v = *(const uint4*)&wo_s[bidx];
            B2.v = *(const uint4*)&wo_s[bidx + 4096];
            B3.v = *(const uint4*)&wo_s[bidx + 8192];
            a = __builtin_amdgcn_mfma_f32_16x16x32_bf16(aA1[kt].f, B1.f, a, 0, 0, 0);
            a = __builtin_amdgcn_mfma_f32_16x16x32_bf16(aA1[kt].f, B2.f, a, 0, 0, 0);
            a = __builtin_amdgcn_mfma_f32_16x16x32_bf16(aA2[kt].f, B3.f, a, 0, 0, 0);
        }
        awo[nt] = a;
    }
    // C layout: row = quad*4+reg (block-row 16w+...), col_out = nt*16 + col
    float x1n[4][4];                    // [nt][reg]
    float s1[4] = {0,0,0,0}, s2[4] = {0,0,0,0};
    #pragma unroll
    for (int nt=0; nt<4; nt++){
        float wb = wo_b[nt*16 + col];
        #pragma unroll
        for (int reg=0; reg<4; reg++){
            int rg = t0 + 16*w + quad*4 + reg;
            size_t xi = ((size_t)b*LSEQ + rg)*DM + nt*16 + col;
            float xv = x1[xi] + awo[nt][reg] + wb;
            x1[xi] = xv;
            x1n[nt][reg] = xv;
            s1[reg] += xv; s2[reg] += xv*xv;
        }
    }
    #pragma unroll
    for (int reg=0; reg<4; reg++){
        float a = s1[reg], q = s2[reg];
        a += __shfl_xor(a,1); a += __shfl_xor(a,2); a += __shfl_xor(a,4); a += __shfl_xor(a,8);
        q += __shfl_xor(q,1); q += __shfl_xor(q,2); q += __shfl_xor(q,4); q += __shfl_xor(q,8);
        s1[reg] = a; s2[reg] = q;
    }
    float rstd[4], mean[4];
    #pragma unroll
    for (int reg=0; reg<4; reg++){
        mean[reg] = s1[reg]*(1.f/64.f);
        float var = s2[reg]*(1.f/64.f) - mean[reg]*mean[reg];
        rstd[reg] = 1.f/sqrtf(var + 1e-5f);
    }
    #pragma unroll
    for (int nt=0; nt<4; nt++){
        int d = nt*16 + col;
        float gv = g2[d], bv = b2t[d];
        #pragma unroll
        for (int reg=0; reg<4; reg++){
            int row = 16*w + quad*4 + reg;
            float xv = (x1n[nt][reg]-mean[reg])*rstd[reg]*gv + bv;
            unsigned h_, m_, l_;
            split3(xv, h_, m_, l_);
            int word = d ^ ((row & 7) << 2);
            xA1[row*64 + word] = h_ | (m_<<16);
            xA2[row*64 + word] = h_ | (l_<<16);
        }
    }

    // hoist W1 A-frags (K=64, reused across all chunks); lane A-row = 16w+col
    FU4 xa1[4], xa2[4];
    {
        int arow = 16*w + col;
        int sw = (col & 7) << 2;
        #pragma unroll
        for (int kt=0; kt<4; kt++){
            int word = (kt*16 + quad*4) ^ sw;
            xa1[kt].v = *(const uint4*)&xA1[arow*64 + word];
            xa2[kt].v = *(const uint4*)&xA2[arow*64 + word];
        }
    }

    // ---- phase 2: W1 + gelu -> gmid A-arrays; W2 partial accumulate. 4 chunks of 64 mid-cols ----
    frag_c aw2[4] = {{0,0,0,0},{0,0,0,0},{0,0,0,0},{0,0,0,0}};
    for (int ch = 0; ch < 4; ch++){
        #pragma unroll
        for (int ntl=0; ntl<4; ntl++){
            int nt = ch*4 + ntl;
            frag_c a = {0.f,0.f,0.f,0.f};
            #pragma unroll
            for (int kt=0; kt<4; kt++){
                FU4 B1, B2, B3;
                int bidx = ((kt*16 + nt)*16 + col)*16 + quad*4;
                B1.v = *(const uint4*)&w1_s[bidx];
                B2.v = *(const uint4*)&w1_s[bidx + 16384];
                B3.v = *(const uint4*)&w1_s[bidx + 32768];
                a = __builtin_amdgcn_mfma_f32_16x16x32_bf16(xa1[kt].f, B1.f, a, 0, 0, 0);
                a = __builtin_amdgcn_mfma_f32_16x16x32_bf16(xa1[kt].f, B2.f, a, 0, 0, 0);
                a = __builtin_amdgcn_mfma_f32_16x16x32_bf16(xa2[kt].f, B3.f, a, 0, 0, 0);
            }
            float bb = b1[nt*16 + col];
            #pragma unroll
            for (int reg=0; reg<4; reg++){
                float xx = a[reg] + bb;
                float ge = 0.5f*xx*(1.f + erff(xx*0.70710678118654752f));
                unsigned h_, m_, l_;
                split3(ge, h_, m_, l_);
                int row = 16*w + quad*4 + reg;
                int word = (ntl*16 + col) ^ ((row & 7) << 2);
                gA1[row*64 + word] = h_ | (m_<<16);
                gA2[row*64 + word] = h_ | (l_<<16);
            }
        }
        // W2 partial: local ktiles 0..3 map to global ktile ch*4+kt2
        int arow = 16*w + col;
        int sw = (col & 7) << 2;
        #pragma unroll
        for (int kt2=0; kt2<4; kt2++){
            FU4 A1, A2;
            int word = (kt2*16 + quad*4) ^ sw;
            A1.v = *(const uint4*)&gA1[arow*64 + word];
            A2.v = *(const uint4*)&gA2[arow*64 + word];
            int kg = ch*4 + kt2;
            #pragma unroll
            for (int nt2=0; nt2<4; nt2++){
                FU4 B1, B2, B3;
                int bidx = ((kg*4 + nt2)*16 + col)*16 + quad*4;
                B1.v = *(const uint4*)&w2_s[bidx];
                B2.v = *(const uint4*)&w2_s[bidx + 16384];
                B3.v = *(const uint4*)&w2_s[bidx + 32768];
                aw2[nt2] = __builtin_amdgcn_mfma_f32_16x16x32_bf16(A1.f, B1.f, aw2[nt2], 0, 0, 0);
                aw2[nt2] = __builtin_amdgcn_mfma_f32_16x16x32_bf16(A1.f, B2.f, aw2[nt2], 0, 0, 0);
                aw2[nt2] = __builtin_amdgcn_mfma_f32_16x16x32_bf16(A2.f, B3.f, aw2[nt2], 0, 0, 0);
            }
        }
    }

    // ---- phase 3: x2 residual ----
    #pragma unroll
    for (int nt=0; nt<4; nt++){
        float bb = b2f[nt*16 + col];
        #pragma unroll
        for (int reg=0; reg<4; reg++){
            int rg = t0 + 16*w + quad*4 + reg;
            size_t xi = ((size_t)b*LSEQ + rg)*DM + nt*16 + col;
            x2[xi] += aw2[nt][reg] + bb;
        }
    }
}

// ---------------- output proj: y = 0.5*(x1+x2) @ out_w + out_b, crop to 1250 ----------------
__global__ __launch_bounds__(256) void k_out(
    const float* __restrict__ x1, const float* __restrict__ x2,
    const float* __restrict__ out_w, const float* __restrict__ out_b, float* __restrict__ y)
{
    int idx = blockIdx.x * 256 + threadIdx.x;
    if (idx >= NBATCH * L0SEQ) return;
    int b = idx / L0SEQ, t = idx % L0SEQ;
    const float* r1 = x1 + ((size_t)b*LSEQ + t)*DM;
    const float* r2 = x2 + ((size_t)b*LSEQ + t)*DM;
    float s = 0.f;
    for (int d = 0; d < DM; d++) s += (r1[d]+r2[d])*0.5f*out_w[d];
    y[idx] = s + out_b[0];
}

extern "C" void kernel_launch(void* const* d_in, const int* in_sizes, int n_in,
                              void* d_out, int out_size, void* d_ws, size_t ws_size,
                              hipStream_t stream)
{
    const float* wave  = (const float*)d_in[0];
    const float* in_w  = (const float*)d_in[1];
    const float* in_b  = (const float*)d_in[2];
    const float* ln1_g = (const float*)d_in[3];
    const float* ln1_b = (const float*)d_in[4];
    const float* wqk   = (const float*)d_in[5];
    const float* wv    = (const float*)d_in[6];
    const float* wo_w  = (const float*)d_in[7];
    const float* wo_b  = (const float*)d_in[8];
    const float* rot   = (const float*)d_in[9];
    const float* ln2_g = (const float*)d_in[10];
    const float* ln2_b = (const float*)d_in[11];
    const float* w1    = (const float*)d_in[12];
    const float* b1    = (const float*)d_in[13];
    const float* w2    = (const float*)d_in[14];
    const float* b2    = (const float*)d_in[15];
    const float* out_w = (const float*)d_in[16];
    const float* out_b = (const float*)d_in[17];
    float* y = (float*)d_out;

    float* ws = (float*)d_ws;
    float* x1     = ws;                  // XSZ
    float* x2     = x1 + XSZ;            // XSZ
    float* qkb    = x2 + XSZ;            // QKSZ
    float* vb     = qkb + QKSZ;          // QKSZ
    float* o_hash = vb + QKSZ;           // OHSZ
    float* slogb  = o_hash + OHSZ;       // SLSZ
    int* buckets  = (int*)(slogb + SLSZ); // SLSZ ints
    int* sorted   = buckets + SLSZ;      // SLSZ ints
    unsigned* wsplit = (unsigned*)(sorted + SLSZ); // 442368 u32 (~1.77 MB)

    k_prep<<<576, 256, 0, stream>>>(wo_w, w1, w2, wsplit);
    k_embed<<<XSZ/256, 256, 0, stream>>>(wave, in_w, in_b, x1, x2);
    for (int layer = 0; layer < 4; layer++) {
        k_qkv<<<320, 256, 0, stream>>>(x2, ln1_g + layer*64, ln1_b + layer*64,
                                       wqk + layer*4096, wv + layer*4096, rot + layer*640,
                                       qkb, vb, buckets);
        k_sort<<<256, 64, 0, stream>>>(buckets, sorted);
        k_attn<<<NBH*NCHUNK, 256, 0, stream>>>(qkb, vb, sorted, o_hash, slogb);
        k_tail<<<320, 256, 0, stream>>>(o_hash, slogb,
                                        wsplit + layer*12288, wo_b + layer*64,
                                        ln2_g + layer*64, ln2_b + layer*64,
                                        wsplit + 49152 + layer*49152, b1 + layer*256,
                                        wsplit + 245760 + layer*49152, b2 + layer*64,
                                        x1, x2);
    }
    k_out<<<(NBATCH*L0SEQ + 255)/256, 256, 0, stream>>>(x1, x2, out_w, out_b, y);
}